// Round 1
// baseline (106.732 us; speedup 1.0000x reference)
//
#include <hip/hip_runtime.h>
#include <math.h>

// rbfLayer: N=100k points, DEG=16 neighbors, NB=MB=4 bases, FIN=FOUT=8.
// out[u,i] = sum_{e in u} sum_{n,m,j} c_e[n] f_e[m] K[i,j,n,m] feat[nbr_e, j]
// Strategy: per-point moment tensor G[n,m,j] accumulated over edges (128 FMA/edge),
// then one K-contraction per point. 2 threads per point (j split 4+4), G=64 regs.

#define FIN 8
#define FOUT 8

__global__ __launch_bounds__(256) void rbf_kernel(
    const float* __restrict__ positions,
    const float* __restrict__ features,
    const float* __restrict__ kern,
    const int*   __restrict__ neighbors,
    const int*   __restrict__ row_splits,
    float*       __restrict__ out,
    int npts)
{
    __shared__ float Kl[1024];   // K[i][j][n][m], i*128 + j*16 + n*4 + m
    {
        const float4* src = (const float4*)kern;
        float4* dst = (float4*)Kl;
        if (threadIdx.x < 256) dst[threadIdx.x] = src[threadIdx.x];
    }
    __syncthreads();

    int gt   = blockIdx.x * blockDim.x + threadIdx.x;
    int u    = gt >> 1;
    int half = gt & 1;
    if (u >= npts) return;

    float2 pu = ((const float2*)positions)[u];
    int rs0 = row_splits[u];
    int rs1 = row_splits[u + 1];

    // G[nm][j] for this thread's j-half
    float g[16][4];
#pragma unroll
    for (int nm = 0; nm < 16; ++nm)
#pragma unroll
        for (int j = 0; j < 4; ++j) g[nm][j] = 0.0f;

    const float INV_PI = 0.31830988618379067f;

    for (int e = rs0; e < rs1; ++e) {
        int nb = neighbors[e];
        float2 pn = ((const float2*)positions)[nb];
        float dx = pn.x - pu.x;
        float dy = pn.y - pu.y;
        float dist = sqrtf(dx * dx + dy * dy);
        // radial: x = dist/SUPPORT*2-1 = dist-1; t = (x+1)/(2/3) = 1.5*dist
        float tr = dist * 1.5f;
        float theta = atan2f(dy, dx);
        float ta = fmaf(theta, INV_PI, 1.0f) * 2.0f;   // in [0,4]

        float c[4], f[4];
#pragma unroll
        for (int n = 0; n < 4; ++n) {
            float d = fabsf(tr - (float)n);
            c[n] = fmaxf(1.0f - d, 0.0f);
        }
#pragma unroll
        for (int m = 0; m < 4; ++m) {
            float d0 = fabsf(ta - (float)m);
            float d1 = fabsf(ta - (float)m - 4.0f);
            float d2 = fabsf(ta - (float)m + 4.0f);
            float d  = fminf(d0, fminf(d1, d2));
            f[m] = fmaxf(1.0f - d, 0.0f);
        }

        float4 fv = ((const float4*)features)[nb * 2 + half];
        float fvj[4] = {fv.x, fv.y, fv.z, fv.w};

#pragma unroll
        for (int n = 0; n < 4; ++n)
#pragma unroll
            for (int m = 0; m < 4; ++m) {
                float w = c[n] * f[m];
#pragma unroll
                for (int j = 0; j < 4; ++j)
                    g[n * 4 + m][j] = fmaf(w, fvj[j], g[n * 4 + m][j]);
            }
    }

    // Final contraction: o[i] = sum_{j in half, nm} K[i, jg, nm] * g[nm][j]
    float o[8];
#pragma unroll
    for (int i = 0; i < 8; ++i) o[i] = 0.0f;

    const float4* K4 = (const float4*)Kl;
#pragma unroll
    for (int i = 0; i < 8; ++i) {
#pragma unroll
        for (int j = 0; j < 4; ++j) {
            int jg = half * 4 + j;
            int base4 = (i * 128 + jg * 16) >> 2;   // float4 index
#pragma unroll
            for (int q = 0; q < 4; ++q) {
                float4 kv = K4[base4 + q];
                o[i] = fmaf(kv.x, g[q * 4 + 0][j], o[i]);
                o[i] = fmaf(kv.y, g[q * 4 + 1][j], o[i]);
                o[i] = fmaf(kv.z, g[q * 4 + 2][j], o[i]);
                o[i] = fmaf(kv.w, g[q * 4 + 3][j], o[i]);
            }
        }
    }

    // Pair reduction: threads (2u, 2u+1) are adjacent lanes in the same wave.
#pragma unroll
    for (int i = 0; i < 8; ++i)
        o[i] += __shfl_xor(o[i], 1);

    float4 ov = (half == 0) ? make_float4(o[0], o[1], o[2], o[3])
                            : make_float4(o[4], o[5], o[6], o[7]);
    ((float4*)out)[u * 2 + half] = ov;   // coalesced float4 store
}

extern "C" void kernel_launch(void* const* d_in, const int* in_sizes, int n_in,
                              void* d_out, int out_size, void* d_ws, size_t ws_size,
                              hipStream_t stream) {
    const float* positions  = (const float*)d_in[0];
    const float* features   = (const float*)d_in[1];
    const float* kern       = (const float*)d_in[2];
    const int*   neighbors  = (const int*)d_in[3];
    const int*   row_splits = (const int*)d_in[4];
    float* out = (float*)d_out;

    int npts = in_sizes[0] / 2;
    int total = npts * 2;
    int block = 256;
    int grid = (total + block - 1) / block;
    rbf_kernel<<<grid, block, 0, stream>>>(positions, features, kern,
                                           neighbors, row_splits, out, npts);
}

// Round 2
// 104.584 us; speedup vs baseline: 1.0205x; 1.0205x over previous
//
#include <hip/hip_runtime.h>
#include <math.h>

// rbfLayer: N=100k points, DEG=16 neighbors, NB=MB=4 bases, FIN=FOUT=8.
// out[u,i] = sum_{e in u} sum_{n,m,j} c_e[n] f_e[m] K[i,j,n,m] feat[nbr_e, j]
// Strategy: per-point moment tensor G[n,m,j] accumulated over edges, then one
// K-contraction per point. 4 threads per point: (j-half 0/1) x (edge-half 0/1).
// Each thread: 8 edges, G[16][4] = 64 regs, batched gathers for MLP.

#define FIN 8
#define FOUT 8

__global__ __launch_bounds__(256) void rbf_kernel(
    const float* __restrict__ positions,
    const float* __restrict__ features,
    const float* __restrict__ kern,
    const int*   __restrict__ neighbors,
    const int*   __restrict__ row_splits,
    float*       __restrict__ out,
    int npts)
{
    __shared__ float Kl[1024];   // K[i][j][n][m], i*128 + j*16 + n*4 + m
    {
        const float4* src = (const float4*)kern;
        float4* dst = (float4*)Kl;
        if (threadIdx.x < 256) dst[threadIdx.x] = src[threadIdx.x];
    }
    __syncthreads();

    int gt   = blockIdx.x * blockDim.x + threadIdx.x;
    int u    = gt >> 2;
    int sub  = gt & 3;
    int half = sub & 1;      // j-half: features/K columns [half*4, half*4+4)
    int eh   = sub >> 1;     // edge-half: edges [rs0+eh*8, rs0+eh*8+8)
    if (u >= npts) return;

    float2 pu = ((const float2*)positions)[u];
    int rs0 = row_splits[u];
    int rs1 = row_splits[u + 1];
    int cnt = rs1 - rs0;

    // G[nm][j] for this thread's j-half, accumulated over this thread's edges
    float g[16][4];
#pragma unroll
    for (int nm = 0; nm < 16; ++nm)
#pragma unroll
        for (int j = 0; j < 4; ++j) g[nm][j] = 0.0f;

    const float INV_PI = 0.31830988618379067f;

    if (cnt == 16) {
        // Fast path: 8 edges for this thread, neighbor row is 16B-aligned.
        int e0 = rs0 + eh * 8;
        const int4* nb4 = (const int4*)(neighbors + e0);
        int4 nbA = nb4[0];
        int4 nbB = nb4[1];

#pragma unroll
        for (int grp = 0; grp < 2; ++grp) {
            int nb[4];
            {
                int4 nv = (grp == 0) ? nbA : nbB;
                nb[0] = nv.x; nb[1] = nv.y; nb[2] = nv.z; nb[3] = nv.w;
            }
            // Issue all 8 loads of this group up front (4 pos + 4 feat).
            float2 pn[4];
            float4 fv[4];
#pragma unroll
            for (int k = 0; k < 4; ++k) pn[k] = ((const float2*)positions)[nb[k]];
#pragma unroll
            for (int k = 0; k < 4; ++k) fv[k] = ((const float4*)features)[nb[k] * 2 + half];

#pragma unroll
            for (int k = 0; k < 4; ++k) {
                float dx = pn[k].x - pu.x;
                float dy = pn[k].y - pu.y;
                float dist = sqrtf(dx * dx + dy * dy);
                float tr = dist * 1.5f;                        // radial hat coordinate
                float theta = atan2f(dy, dx);
                float ta = fmaf(theta, INV_PI, 1.0f) * 2.0f;   // angular in [0,4]

                float c[4], f[4];
#pragma unroll
                for (int n = 0; n < 4; ++n) {
                    float d = fabsf(tr - (float)n);
                    c[n] = fmaxf(1.0f - d, 0.0f);
                }
#pragma unroll
                for (int m = 0; m < 4; ++m) {
                    float d0 = fabsf(ta - (float)m);
                    float d1 = fabsf(ta - (float)m - 4.0f);
                    float d2 = fabsf(ta - (float)m + 4.0f);
                    float d  = fminf(d0, fminf(d1, d2));
                    f[m] = fmaxf(1.0f - d, 0.0f);
                }

                float fvj[4] = {fv[k].x, fv[k].y, fv[k].z, fv[k].w};
#pragma unroll
                for (int n = 0; n < 4; ++n)
#pragma unroll
                    for (int m = 0; m < 4; ++m) {
                        float w = c[n] * f[m];
#pragma unroll
                        for (int j = 0; j < 4; ++j)
                            g[n * 4 + m][j] = fmaf(w, fvj[j], g[n * 4 + m][j]);
                    }
            }
        }
    } else {
        // Generic path: split cnt edges between the two edge-halves.
        int c0 = (cnt + 1) >> 1;
        int e0 = rs0 + eh * c0;
        int e1 = (eh == 0) ? (rs0 + c0) : rs1;
        for (int e = e0; e < e1; ++e) {
            int nb = neighbors[e];
            float2 pn = ((const float2*)positions)[nb];
            float dx = pn.x - pu.x;
            float dy = pn.y - pu.y;
            float dist = sqrtf(dx * dx + dy * dy);
            float tr = dist * 1.5f;
            float theta = atan2f(dy, dx);
            float ta = fmaf(theta, INV_PI, 1.0f) * 2.0f;
            float c[4], f[4];
#pragma unroll
            for (int n = 0; n < 4; ++n) {
                float d = fabsf(tr - (float)n);
                c[n] = fmaxf(1.0f - d, 0.0f);
            }
#pragma unroll
            for (int m = 0; m < 4; ++m) {
                float d0 = fabsf(ta - (float)m);
                float d1 = fabsf(ta - (float)m - 4.0f);
                float d2 = fabsf(ta - (float)m + 4.0f);
                float d  = fminf(d0, fminf(d1, d2));
                f[m] = fmaxf(1.0f - d, 0.0f);
            }
            float4 fv = ((const float4*)features)[nb * 2 + half];
            float fvj[4] = {fv.x, fv.y, fv.z, fv.w};
#pragma unroll
            for (int n = 0; n < 4; ++n)
#pragma unroll
                for (int m = 0; m < 4; ++m) {
                    float w = c[n] * f[m];
#pragma unroll
                    for (int j = 0; j < 4; ++j)
                        g[n * 4 + m][j] = fmaf(w, fvj[j], g[n * 4 + m][j]);
                }
        }
    }

    // Final contraction: o[i] = sum_{j in half, nm} K[i, jg, nm] * g[nm][j]
    float o[8];
#pragma unroll
    for (int i = 0; i < 8; ++i) o[i] = 0.0f;

    const float4* K4 = (const float4*)Kl;
#pragma unroll
    for (int i = 0; i < 8; ++i) {
#pragma unroll
        for (int j = 0; j < 4; ++j) {
            int jg = half * 4 + j;
            int base4 = (i * 128 + jg * 16) >> 2;   // float4 index
#pragma unroll
            for (int q = 0; q < 4; ++q) {
                float4 kv = K4[base4 + q];
                o[i] = fmaf(kv.x, g[q * 4 + 0][j], o[i]);
                o[i] = fmaf(kv.y, g[q * 4 + 1][j], o[i]);
                o[i] = fmaf(kv.z, g[q * 4 + 2][j], o[i]);
                o[i] = fmaf(kv.w, g[q * 4 + 3][j], o[i]);
            }
        }
    }

    // Reduce over the 4 lanes of this point (lanes 4u..4u+3 are wave-adjacent).
#pragma unroll
    for (int i = 0; i < 8; ++i) {
        o[i] += __shfl_xor(o[i], 1);
        o[i] += __shfl_xor(o[i], 2);
    }

    // Each of the 4 lanes stores 2 floats: coalesced float2 stores.
    float2 ov = (sub == 0) ? make_float2(o[0], o[1])
              : (sub == 1) ? make_float2(o[2], o[3])
              : (sub == 2) ? make_float2(o[4], o[5])
                           : make_float2(o[6], o[7]);
    ((float2*)out)[u * 4 + sub] = ov;
}

extern "C" void kernel_launch(void* const* d_in, const int* in_sizes, int n_in,
                              void* d_out, int out_size, void* d_ws, size_t ws_size,
                              hipStream_t stream) {
    const float* positions  = (const float*)d_in[0];
    const float* features   = (const float*)d_in[1];
    const float* kern       = (const float*)d_in[2];
    const int*   neighbors  = (const int*)d_in[3];
    const int*   row_splits = (const int*)d_in[4];
    float* out = (float*)d_out;

    int npts = in_sizes[0] / 2;
    int total = npts * 4;
    int block = 256;
    int grid = (total + block - 1) / block;
    rbf_kernel<<<grid, block, 0, stream>>>(positions, features, kern,
                                           neighbors, row_splits, out, npts);
}